// Round 19
// baseline (749.085 us; speedup 1.0000x reference)
//
#include <hip/hip_runtime.h>
#include <hip/hip_bf16.h>
#include <math.h>

#define B 64
#define CIN 2
#define CH 32
#define H 128
#define W 128
#define MODES 12
#define KY 24              // kept ky rows: 0..11 and 116..127
#define KX 12              // kept kx cols
#define HW (H*W)           // 16384
#define NMODE (KY*KX)      // 288
#define XPAD 132           // LDS row pitch: 132 % 32 == 4 -> b128 banks rotate

typedef float f32x2 __attribute__((ext_vector_type(2)));
typedef unsigned short u16;
typedef unsigned int u32;
__device__ __forceinline__ f32x2 mk2(float a, float b) { f32x2 r; r.x = a; r.y = b; return r; }

// bf16 <-> f32 (h stored as bf16: halves h HBM traffic)
__device__ __forceinline__ float bflo(u32 u) { return __uint_as_float(u << 16); }
__device__ __forceinline__ float bfhi(u32 u) { return __uint_as_float(u & 0xFFFF0000u); }
__device__ __forceinline__ u16 f2bf(float f) {            // RTNE (lift only)
    u32 u = __float_as_uint(f);
    return (u16)((u + 0x7FFFu + ((u >> 16) & 1u)) >> 16);
}
// packed f32x2 -> 2 bf16 in one u32 (compiler: v_cvt_pk_bf16_f32)
__device__ __forceinline__ u32 pk2bf(f32x2 v) {
    __hip_bfloat162 p = __float22bfloat162_rn(make_float2(v.x, v.y));
    return *reinterpret_cast<u32*>(&p);
}

// tanh-form GELU. scalar (head/lift) ...
__device__ __forceinline__ float gelu_f(float x) {
    float x2 = x * x;
    float d  = x * (1.5957691216057308f + 0.0713548162726009f * x2);  // 2y
    float e  = __expf(d);
    float r  = __builtin_amdgcn_rcpf(e + 1.0f);
    return x - x * r;
}
// ... and packed-pair version for fused.
__device__ __forceinline__ f32x2 gelu2(f32x2 x) {
    const f32x2 c1 = mk2(1.5957691216057308f, 1.5957691216057308f);
    const f32x2 c2 = mk2(0.0713548162726009f, 0.0713548162726009f);
    f32x2 x2 = x * x;                        // pk_mul
    f32x2 d  = x * (c1 + c2 * x2);           // pk_fma + pk_mul
    f32x2 e  = mk2(__expf(d.x), __expf(d.y));
    f32x2 ep = e + mk2(1.0f, 1.0f);          // pk_add
    f32x2 r  = mk2(__builtin_amdgcn_rcpf(ep.x), __builtin_amdgcn_rcpf(ep.y));
    return x - x * r;
}

// ---------------- one setup kernel (tables + weight reorder + ww transpose) -
#define N_TBL (MODES * W + KY * H)           // 4608
#define N_TRN (4 * CH * CH)                  // 4096
#define N_REO (4 * NMODE * CH * CH)          // 1179648
__global__ __launch_bounds__(256) void k_setup(
        float* cWkw, float* sWkw, float* cnsWkw, float* cnsH2, float* mnsH2,
        const float* __restrict__ w1r, const float* __restrict__ w1i,
        const float* __restrict__ w2r, const float* __restrict__ w2i,
        float* __restrict__ wR,
        const float* __restrict__ ww, float* __restrict__ wwT) {
    int t = blockIdx.x * 256 + threadIdx.x;
    const float TWO_PI_OVER = 6.283185307179586476925f / 128.0f;
    if (t < MODES * W) {
        int k = t / W, w = t % W;
        int m = (k * w) & 127;
        float s, c;
        sincosf(TWO_PI_OVER * (float)m, &s, &c);
        cWkw[k * W + w] = c;  sWkw[k * W + w] = s;
        cnsWkw[(k * W + w) * 2]     = c;
        cnsWkw[(k * W + w) * 2 + 1] = -s;
    } else if (t < N_TBL) {
        int u = t - MODES * W;
        int kyI = u / H, hh = u % H;
        int ky = (kyI < MODES) ? kyI : (H - MODES + (kyI - MODES));  // 116..127
        int m = (ky * hh) & 127;
        float s, c;
        sincosf(TWO_PI_OVER * (float)m, &s, &c);
        cnsH2[(hh * KY + kyI) * 2]     = c;
        cnsH2[(hh * KY + kyI) * 2 + 1] = s;
        mnsH2[(hh * KY + kyI) * 2]     = -s;
        mnsH2[(hh * KY + kyI) * 2 + 1] = c;
    } else if (t < N_TBL + N_TRN) {
        int idx = t - N_TBL;
        int l = idx / (CH * CH);
        int r = idx % (CH * CH);
        int i = r / CH, o = r % CH;
        wwT[idx] = ww[l * CH * CH + o * CH + i];
    } else {
        int idx = t - N_TBL - N_TRN;
        if (idx >= N_REO) return;
        int o = idx & 31;
        int i = (idx >> 5) & 31;
        int m = (idx >> 10) % NMODE;
        int layer = idx / (NMODE * CH * CH);
        int kyI = m / KX, kx = m % KX;
        const float *sr, *si;
        int row;
        if (kyI < MODES) { sr = w1r; si = w1i; row = kyI; }
        else             { sr = w2r; si = w2i; row = kyI - MODES; }
        int src = ((layer * CH + i) * CH + o) * (MODES * MODES) + row * MODES + kx;
        wR[(size_t)idx * 2]     = sr[src];
        wR[(size_t)idx * 2 + 1] = si[src];
    }
}

// ---------------- lifting conv3x3 circular: x[B,2,H,W] -> h(bf16) -----------
// 512 thr: thread (w=tid&127, og) does 8 channels. og MUST be readfirstlane'd
// (r17 lesson: plain tid>>7 -> per-lane weight loads -> 95us).
__global__ __launch_bounds__(512) void k_lift(
        const float* __restrict__ x, const float* __restrict__ pw,
        const float* __restrict__ pb, u16* __restrict__ h) {
    int bh = blockIdx.x;            // b*H + hr
    int b = bh >> 7, hr = bh & 127;
    int tid = threadIdx.x;
    int w = tid & 127;
    int og = __builtin_amdgcn_readfirstlane(tid >> 7);   // 0..3, wave-uniform
    int wl = (w + W - 1) & (W - 1), wr2 = (w + 1) & (W - 1);
    float xv[CIN][3][3];
    #pragma unroll
    for (int ic = 0; ic < CIN; ++ic) {
        const float* xc = x + (size_t)(b * CIN + ic) * HW;
        #pragma unroll
        for (int r = 0; r < 3; ++r) {
            int hh = (hr + r - 1 + H) & (H - 1);
            const float* xr = xc + hh * W;
            xv[ic][r][0] = xr[wl];
            xv[ic][r][1] = xr[w];
            xv[ic][r][2] = xr[wr2];
        }
    }
    #pragma unroll
    for (int j = 0; j < 8; ++j) {
        int o = og * 8 + j;
        float acc = pb[o];                       // uniform -> s_load
        const float* wo = pw + o * CIN * 9;      // uniform
        #pragma unroll
        for (int ic = 0; ic < CIN; ++ic)
            #pragma unroll
            for (int r = 0; r < 3; ++r)
                #pragma unroll
                for (int c3 = 0; c3 < 3; ++c3)
                    acc += xv[ic][r][c3] * wo[ic * 9 + r * 3 + c3];
        h[(size_t)(b * CH + o) * HW + hr * W + w] = f2bf(acc);
    }
}

// ---------------- DFT along W: h(bf16) rows -> Xw[row][k]{re,im} ------------
// v6: 384 thr (6 waves) -> 24 waves/CU. Wave kp=tid>>6 (0..5) owns 2 modes.
// LDS pitch 132 keeps ds_read_b128 banks rotated; staging conflict-free.
__global__ __launch_bounds__(384) void k_dft_w(
        const u16* __restrict__ h, const float* __restrict__ cnsWkw,
        float* __restrict__ Xw) {
    __shared__ float xs[64 * XPAD];      // 33.8 KB
    int row0 = blockIdx.x * 64;
    int tid = threadIdx.x;               // 0..383
    const uint2* src = (const uint2*)h;  // 4 bf16 per uint2
    #pragma unroll
    for (int it = 0; it < 6; ++it) {     // 2048 float4-slots
        int idx = it * 384 + tid;
        if (idx < 2048) {
            int r = idx >> 5, f4c = idx & 31;
            uint2 v = src[(size_t)(row0 + r) * 32 + f4c];
            float4 f;
            f.x = bflo(v.x); f.y = bfhi(v.x);
            f.z = bflo(v.y); f.w = bfhi(v.y);
            *(float4*)(xs + r * XPAD + f4c * 4) = f;
        }
    }
    __syncthreads();
    int r = tid & 63;
    int kp = __builtin_amdgcn_readfirstlane(tid >> 6);   // 0..5, wave-uniform
    const f32x2* tw = (const f32x2*)cnsWkw + kp * 2 * W; // modes 2kp, 2kp+1
    f32x2 a0 = mk2(0.f, 0.f), a1 = mk2(0.f, 0.f);
    const float4* xr4 = (const float4*)(xs + r * XPAD);
    #pragma unroll 4
    for (int w4 = 0; w4 < W / 4; ++w4) {
        float4 xv = xr4[w4];             // ds_read_b128, rotated banks
        int w = w4 * 4;
        const f32x2* t0 = tw + w;        // uniform -> batched s_loads
        const f32x2* t1 = tw + W + w;
        a0 += mk2(xv.x, xv.x) * t0[0];  a1 += mk2(xv.x, xv.x) * t1[0];
        a0 += mk2(xv.y, xv.y) * t0[1];  a1 += mk2(xv.y, xv.y) * t1[1];
        a0 += mk2(xv.z, xv.z) * t0[2];  a1 += mk2(xv.z, xv.z) * t1[2];
        a0 += mk2(xv.w, xv.w) * t0[3];  a1 += mk2(xv.w, xv.w) * t1[3];
    }
    float2* dst = (float2*)(Xw + (size_t)(row0 + r) * MODES * 2) + kp * 2;
    dst[0] = make_float2(a0.x, a0.y);
    dst[1] = make_float2(a1.x, a1.y);
}

// ---------------- DFT along H: Xw -> Xf[m][b*CH+c]{re,im} -------------------
__global__ __launch_bounds__(320) void k_dft_h(
        const float* __restrict__ Xw, const float* __restrict__ cnsH2,
        float* __restrict__ Xf) {
    __shared__ float4 xs4[H * KX / 2];   // 12 KB, aliased as float2[H][KX]
    const float2* xs = (const float2*)xs4;
    int bc = blockIdx.x;                 // 0..B*CH-1
    int tid = threadIdx.x;               // 0..319
    const float4* src = (const float4*)(Xw + (size_t)bc * H * KX * 2);
    #pragma unroll
    for (int r = 0; r < 3; ++r) {        // 768 float4 staged by 320 threads
        int idx = r * 320 + tid;
        if (idx < H * KX / 2) xs4[idx] = src[idx];
    }
    __syncthreads();
    if (tid < KY * KX) {                 // m = tid = ky*KX+kx
        int ky = tid / KX, kx = tid % KX;
        const float2* cs = (const float2*)cnsH2 + ky;   // [hh][ky] stride KY
        float ar = 0.f, ai = 0.f;
        #pragma unroll 4
        for (int hh = 0; hh < H; ++hh) {
            float2 v = xs[hh * KX + kx];                 // LDS broadcast groups
            float2 t = cs[hh * KY];                      // L1-resident table
            ar += v.x * t.x + v.y * t.y;                 // (xr+ixi)(c-is)
            ai += v.y * t.x - v.x * t.y;
        }
        ((float2*)Xf)[(size_t)tid * (B * CH) + bc] = make_float2(ar, ai);
    }
}

// ---------------- spectral channel mix: per mode, Y[b,o] = sum_i X[b,i]W[i,o]
// v2: grid (288,4) -> 1152 blocks (was 288 = 1 blk/CU, latency-starved).
// Each thread handles 2 b's (acc2[2]); X/W rows L2-shared across y-blocks.
__global__ __launch_bounds__(256) void k_specmul(
        const float* __restrict__ Xf, const float* __restrict__ wRl,
        float* __restrict__ Yt) {
    int m = blockIdx.x;                 // 0..287
    int o = threadIdx.x & 31;
    int bq = threadIdx.x >> 5;          // 0..7
    int b0 = blockIdx.y * 16 + bq * 2;  // 2 consecutive b's per thread
    const f32x2* X  = (const f32x2*)Xf  + (size_t)m * (B * CH);
    const f32x2* Wm = (const f32x2*)wRl + (size_t)m * (CH * CH);
    f32x2 acc2[2];
    acc2[0] = mk2(0.f, 0.f);  acc2[1] = mk2(0.f, 0.f);
    for (int i = 0; i < CH; ++i) {
        f32x2 wv  = Wm[i * CH + o];     // coalesced across lanes
        f32x2 wvB = mk2(-wv.y, wv.x);
        #pragma unroll
        for (int j = 0; j < 2; ++j) {
            f32x2 xv = X[(b0 + j) * CH + i];   // L1/L2 broadcast
            acc2[j] += mk2(xv.x, xv.x) * wv + mk2(xv.y, xv.y) * wvB;  // 2 pk_fma
        }
    }
    float2* Yp = (float2*)Yt;
    #pragma unroll
    for (int j = 0; j < 2; ++j)
        Yp[((size_t)(b0 + j) * NMODE + m) * CH + o] = make_float2(acc2[j].x, acc2[j].y);
}

// ---------------- inverse DFT along H: Yt -> Zt[b][h][p][kx][o], pre-scaled -
// v2: grid (B,16), 8 rows/block -> 1024 blocks (was 512; latency hiding).
__global__ __launch_bounds__(384) void k_idft_h(
        const float* __restrict__ Yt, const float* __restrict__ cnsH2,
        const float* __restrict__ mnsH2, float* __restrict__ Zt) {
    int b = blockIdx.x;
    int hh0 = blockIdx.y * 8;            // 16 chunks of 8 rows
    int o = threadIdx.x & 31;
    int kx = threadIdx.x >> 5;           // 0..11
    float yr[KY], yi[KY];
    #pragma unroll
    for (int ky = 0; ky < KY; ++ky) {
        float2 v = ((const float2*)Yt)[((size_t)b * NMODE + ky * KX + kx) * CH + o];
        yr[ky] = v.x;  yi[ky] = v.y;
    }
    float sc = (kx == 0 ? 1.0f : 2.0f) / (float)HW;
    #pragma unroll 2
    for (int hr = 0; hr < 8; ++hr) {
        int hh = hh0 + hr;
        const f32x2* cs = (const f32x2*)(cnsH2 + hh * KY * 2);  // uniform
        const f32x2* ms = (const f32x2*)(mnsH2 + hh * KY * 2);  // uniform
        f32x2 a = mk2(0.f, 0.f);
        #pragma unroll
        for (int ky = 0; ky < KY; ++ky)
            a += mk2(yr[ky], yr[ky]) * cs[ky] + mk2(yi[ky], yi[ky]) * ms[ky];
        size_t base = ((size_t)(b * H + hh) * 2) * (KX * CH) + kx * CH + o;
        Zt[base]            = a.x * sc;
        Zt[base + KX * CH]  = a.y * sc;
    }
}

// ---------------- fused: pointwise GEMM + irfft(W) + bias + GELU ------------
// r15/r16 body FROZEN (84.5us equilibrium; VALU cuts no longer move it).
template <int LAST>
__global__ __launch_bounds__(512, 4) void k_fused(
        u16* __restrict__ h, const float* __restrict__ Zt,
        const float* __restrict__ wwT, const float* __restrict__ wb,
        const float* __restrict__ cWkw, const float* __restrict__ sWkw,
        float* __restrict__ part) {
    __shared__ float hs[CH * W];         // 16 KB
    __shared__ float red[8][8];          // wave partials (LAST=1 only)
    int bh = blockIdx.x;                 // b*H + hr
    int b = bh >> 7, hr = bh & 127;
    int tid = threadIdx.x;
    int w = tid & 127;
    int og = __builtin_amdgcn_readfirstlane(tid >> 7);   // wave-uniform 0..3
    const uint2* hrow2 = (const uint2*)(h + (size_t)b * CH * HW + hr * W);
    #pragma unroll
    for (int p = 0; p < 2; ++p) {        // 1024 float4-slots, conflict-free
        int idx = p * 512 + tid;
        int i = idx >> 5, f4c = idx & 31;
        uint2 v = hrow2[(size_t)i * (HW / 4) + f4c];
        float4 f;
        f.x = bflo(v.x); f.y = bfhi(v.x);
        f.z = bflo(v.y); f.w = bfhi(v.y);
        *(float4*)(hs + i * W + f4c * 4) = f;
    }
    float ck[MODES], nsk[MODES];
    #pragma unroll
    for (int k = 0; k < MODES; ++k) {
        ck[k]  = cWkw[k * W + w];        // per-lane, coalesced, L1-hot
        nsk[k] = -sWkw[k * W + w];
    }
    f32x2 acc2[4];
    const f32x2* wb2 = (const f32x2*)(wb + og * 8);      // uniform
    #pragma unroll
    for (int j = 0; j < 4; ++j) acc2[j] = wb2[j];
    __syncthreads();
    // pointwise: acc2[j] += hs[i][w] * wwT[i][og*8+2j..2j+1]
    #pragma unroll 4
    for (int i = 0; i < CH; ++i) {
        float hv = hs[i * W + w];
        f32x2 hv2 = mk2(hv, hv);
        const f32x2* wt2 = (const f32x2*)(wwT + i * CH + og * 8);  // uniform
        #pragma unroll
        for (int j = 0; j < 4; ++j) acc2[j] += hv2 * wt2[j];       // pk_fma
    }
    // spectral: acc2[j] += zr*ck - zi*sk  (pre-scaled in Zt)
    const float* Zb = Zt + ((size_t)bh * 2) * (KX * CH) + og * 8;
    #pragma unroll
    for (int k = 0; k < MODES; ++k) {
        const f32x2* zr2 = (const f32x2*)(Zb + k * CH);            // uniform
        const f32x2* zi2 = (const f32x2*)(Zb + k * CH + KX * CH);
        f32x2 ck2  = mk2(ck[k], ck[k]);
        f32x2 nsk2 = mk2(nsk[k], nsk[k]);
        #pragma unroll
        for (int j = 0; j < 4; ++j)
            acc2[j] += zr2[j] * ck2 + zi2[j] * nsk2;               // 2 pk_fma
    }
    if (LAST == 0) {
        u16* hout = h + (size_t)(b * CH + og * 8) * HW + hr * W + w;
        #pragma unroll
        for (int j = 0; j < 4; ++j) {
            u32 pk = pk2bf(gelu2(acc2[j]));          // v_cvt_pk_bf16_f32
            hout[(size_t)(2 * j)     * HW] = (u16)pk;
            hout[(size_t)(2 * j + 1) * HW] = (u16)(pk >> 16);
        }
    } else {
        float v[8];
        #pragma unroll
        for (int j = 0; j < 4; ++j) {
            f32x2 g = gelu2(acc2[j]);
            v[2 * j]     = g.x;
            v[2 * j + 1] = g.y;
        }
        #pragma unroll
        for (int j = 0; j < 8; ++j)
            #pragma unroll
            for (int off = 32; off > 0; off >>= 1)
                v[j] += __shfl_xor(v[j], off, 64);
        int wave = tid >> 6;             // 0..7 (wave>>1 == og)
        if ((tid & 63) == 0) {
            #pragma unroll
            for (int j = 0; j < 8; ++j) red[wave][j] = v[j];
        }
        __syncthreads();
        if (tid < CH) {                  // c = tid: og=c>>3, j=c&7
            float p = red[2 * (tid >> 3)][tid & 7] + red[2 * (tid >> 3) + 1][tid & 7];
            part[((size_t)b * CH + tid) * H + hr] = p;
        }
    }
}

// ---------------- head MLP (k_reduce folded in): part -> g -> 128 -> 1 ------
__global__ __launch_bounds__(128) void k_head(
        const float* __restrict__ part, const float* __restrict__ q1w,
        const float* __restrict__ q1b, const float* __restrict__ q2w,
        const float* __restrict__ q2b, float* __restrict__ out) {
    __shared__ float red3[CH][4];
    __shared__ float gs[CH];
    __shared__ float red2[2];
    int b = blockIdx.x;
    int t = threadIdx.x;
    {   // reduce part[(b,c)][0..127]: thread (c = t>>2, quarter q = t&3)
        const float* p = part + ((size_t)b * CH + (t >> 2)) * H + (t & 3) * 32;
        float s = 0.f;
        #pragma unroll
        for (int j = 0; j < 32; ++j) s += p[j];
        red3[t >> 2][t & 3] = s;
    }
    __syncthreads();
    if (t < CH)
        gs[t] = (red3[t][0] + red3[t][1] + red3[t][2] + red3[t][3]) * (1.0f / (float)HW);
    __syncthreads();
    float a = q1b[t];
    #pragma unroll
    for (int c = 0; c < CH; ++c) a += gs[c] * q1w[t * CH + c];
    a = gelu_f(a);
    float hsum = a * q2w[t];
    #pragma unroll
    for (int off = 32; off > 0; off >>= 1) hsum += __shfl_down(hsum, off, 64);
    if ((t & 63) == 0) red2[t >> 6] = hsum;
    __syncthreads();
    if (t == 0) {
        float logit = red2[0] + red2[1] + q2b[0];
        out[b] = 1.0f / (1.0f + expf(-logit));
    }
}

extern "C" void kernel_launch(void* const* d_in, const int* in_sizes, int n_in,
                              void* d_out, int out_size, void* d_ws, size_t ws_size,
                              hipStream_t stream) {
    const float* x   = (const float*)d_in[0];
    const float* p_w = (const float*)d_in[1];
    const float* p_b = (const float*)d_in[2];
    const float* w1r = (const float*)d_in[3];
    const float* w1i = (const float*)d_in[4];
    const float* w2r = (const float*)d_in[5];
    const float* w2i = (const float*)d_in[6];
    const float* ww  = (const float*)d_in[7];
    const float* wb  = (const float*)d_in[8];
    const float* q1w = (const float*)d_in[9];
    const float* q1b = (const float*)d_in[10];
    const float* q2w = (const float*)d_in[11];
    const float* q2b = (const float*)d_in[12];
    float* out = (float*)d_out;

    float* ws = (float*)d_ws;
    size_t off = 0;
    auto alloc = [&](size_t n) {
        float* p = ws + off;
        off += (n + 63) & ~(size_t)63;   // 256B-align
        return p;
    };
    float* cWkw   = alloc(MODES * W);
    float* sWkw   = alloc(MODES * W);
    float* cnsWkw = alloc(MODES * W * 2);
    float* cnsH2  = alloc(H * KY * 2);
    float* mnsH2  = alloc(H * KY * 2);
    u16*   hBuf = (u16*)alloc((size_t)B * CH * HW / 2);  // 67 MB bf16
    float* XwZ  = alloc((size_t)B * CH * H * KX * 2);    // 25 MB (Xw, reused as Zt)
    float* Xf   = alloc((size_t)NMODE * B * CH * 2);     // 4.7 MB
    float* Yt   = alloc((size_t)B * NMODE * CH * 2);     // 4.7 MB
    float* wR   = alloc((size_t)4 * NMODE * CH * CH * 2);// 9.4 MB
    float* wwT  = alloc(4 * CH * CH);
    float* part = alloc((size_t)B * CH * H);             // 1 MB block partials

    // one setup kernel: tables + ww transpose + weight reorder
    k_setup<<<(N_TBL + N_TRN + N_REO + 255) / 256, 256, 0, stream>>>(
        cWkw, sWkw, cnsWkw, cnsH2, mnsH2, w1r, w1i, w2r, w2i, wR, ww, wwT);

    k_lift<<<B * H, 512, 0, stream>>>(x, p_w, p_b, hBuf);

    for (int layer = 0; layer < 4; ++layer) {
        k_dft_w<<<(B * CH * H) / 64, 384, 0, stream>>>(hBuf, cnsWkw, XwZ);
        k_dft_h<<<B * CH, 320, 0, stream>>>(XwZ, cnsH2, Xf);
        k_specmul<<<dim3(NMODE, 4), 256, 0, stream>>>(
            Xf, wR + (size_t)layer * NMODE * CH * CH * 2, Yt);
        k_idft_h<<<dim3(B, 16), 384, 0, stream>>>(Yt, cnsH2, mnsH2, XwZ);
        if (layer < 3)
            k_fused<0><<<B * H, 512, 0, stream>>>(
                hBuf, XwZ, wwT + layer * CH * CH, wb + layer * CH, cWkw, sWkw, part);
        else
            k_fused<1><<<B * H, 512, 0, stream>>>(
                hBuf, XwZ, wwT + layer * CH * CH, wb + layer * CH, cWkw, sWkw, part);
    }

    k_head<<<B, 128, 0, stream>>>(part, q1w, q1b, q2w, q2b, out);
}

// Round 20
// 731.732 us; speedup vs baseline: 1.0237x; 1.0237x over previous
//
#include <hip/hip_runtime.h>
#include <hip/hip_bf16.h>
#include <math.h>

#define B 64
#define CIN 2
#define CH 32
#define H 128
#define W 128
#define MODES 12
#define KY 24              // kept ky rows: 0..11 and 116..127
#define KX 12              // kept kx cols
#define HW (H*W)           // 16384
#define NMODE (KY*KX)      // 288
#define XPAD 132           // LDS row pitch: 132 % 32 == 4 -> b128 banks rotate

typedef float f32x2 __attribute__((ext_vector_type(2)));
typedef unsigned short u16;
typedef unsigned int u32;
__device__ __forceinline__ f32x2 mk2(float a, float b) { f32x2 r; r.x = a; r.y = b; return r; }

// bf16 <-> f32 (h stored as bf16: halves h HBM traffic)
__device__ __forceinline__ float bflo(u32 u) { return __uint_as_float(u << 16); }
__device__ __forceinline__ float bfhi(u32 u) { return __uint_as_float(u & 0xFFFF0000u); }
__device__ __forceinline__ u16 f2bf(float f) {            // RTNE (lift only)
    u32 u = __float_as_uint(f);
    return (u16)((u + 0x7FFFu + ((u >> 16) & 1u)) >> 16);
}
// packed f32x2 -> 2 bf16 in one u32 (compiler: v_cvt_pk_bf16_f32)
__device__ __forceinline__ u32 pk2bf(f32x2 v) {
    __hip_bfloat162 p = __float22bfloat162_rn(make_float2(v.x, v.y));
    return *reinterpret_cast<u32*>(&p);
}

// tanh-form GELU. scalar (head/lift) ...
__device__ __forceinline__ float gelu_f(float x) {
    float x2 = x * x;
    float d  = x * (1.5957691216057308f + 0.0713548162726009f * x2);  // 2y
    float e  = __expf(d);
    float r  = __builtin_amdgcn_rcpf(e + 1.0f);
    return x - x * r;
}
// ... and packed-pair version for fused.
__device__ __forceinline__ f32x2 gelu2(f32x2 x) {
    const f32x2 c1 = mk2(1.5957691216057308f, 1.5957691216057308f);
    const f32x2 c2 = mk2(0.0713548162726009f, 0.0713548162726009f);
    f32x2 x2 = x * x;                        // pk_mul
    f32x2 d  = x * (c1 + c2 * x2);           // pk_fma + pk_mul
    f32x2 e  = mk2(__expf(d.x), __expf(d.y));
    f32x2 ep = e + mk2(1.0f, 1.0f);          // pk_add
    f32x2 r  = mk2(__builtin_amdgcn_rcpf(ep.x), __builtin_amdgcn_rcpf(ep.y));
    return x - x * r;
}

// ---------------- one setup kernel (tables + weight reorder + ww transpose) -
#define N_TBL (MODES * W + KY * H)           // 4608
#define N_TRN (4 * CH * CH)                  // 4096
#define N_REO (4 * NMODE * CH * CH)          // 1179648
__global__ __launch_bounds__(256) void k_setup(
        float* cWkw, float* sWkw, float* cnsWkw, float* cnsH2, float* mnsH2,
        const float* __restrict__ w1r, const float* __restrict__ w1i,
        const float* __restrict__ w2r, const float* __restrict__ w2i,
        float* __restrict__ wR,
        const float* __restrict__ ww, float* __restrict__ wwT) {
    int t = blockIdx.x * 256 + threadIdx.x;
    const float TWO_PI_OVER = 6.283185307179586476925f / 128.0f;
    if (t < MODES * W) {
        int k = t / W, w = t % W;
        int m = (k * w) & 127;
        float s, c;
        sincosf(TWO_PI_OVER * (float)m, &s, &c);
        cWkw[k * W + w] = c;  sWkw[k * W + w] = s;
        cnsWkw[(k * W + w) * 2]     = c;
        cnsWkw[(k * W + w) * 2 + 1] = -s;
    } else if (t < N_TBL) {
        int u = t - MODES * W;
        int kyI = u / H, hh = u % H;
        int ky = (kyI < MODES) ? kyI : (H - MODES + (kyI - MODES));  // 116..127
        int m = (ky * hh) & 127;
        float s, c;
        sincosf(TWO_PI_OVER * (float)m, &s, &c);
        cnsH2[(hh * KY + kyI) * 2]     = c;
        cnsH2[(hh * KY + kyI) * 2 + 1] = s;
        mnsH2[(hh * KY + kyI) * 2]     = -s;
        mnsH2[(hh * KY + kyI) * 2 + 1] = c;
    } else if (t < N_TBL + N_TRN) {
        int idx = t - N_TBL;
        int l = idx / (CH * CH);
        int r = idx % (CH * CH);
        int i = r / CH, o = r % CH;
        wwT[idx] = ww[l * CH * CH + o * CH + i];
    } else {
        int idx = t - N_TBL - N_TRN;
        if (idx >= N_REO) return;
        int o = idx & 31;
        int i = (idx >> 5) & 31;
        int m = (idx >> 10) % NMODE;
        int layer = idx / (NMODE * CH * CH);
        int kyI = m / KX, kx = m % KX;
        const float *sr, *si;
        int row;
        if (kyI < MODES) { sr = w1r; si = w1i; row = kyI; }
        else             { sr = w2r; si = w2i; row = kyI - MODES; }
        int src = ((layer * CH + i) * CH + o) * (MODES * MODES) + row * MODES + kx;
        wR[(size_t)idx * 2]     = sr[src];
        wR[(size_t)idx * 2 + 1] = si[src];
    }
}

// ---------------- lifting conv3x3 circular: x[B,2,H,W] -> h(bf16) -----------
// 512 thr: thread (w=tid&127, og) does 8 channels. og MUST be readfirstlane'd
// (r17 lesson: plain tid>>7 -> per-lane weight loads -> 95us).
__global__ __launch_bounds__(512) void k_lift(
        const float* __restrict__ x, const float* __restrict__ pw,
        const float* __restrict__ pb, u16* __restrict__ h) {
    int bh = blockIdx.x;            // b*H + hr
    int b = bh >> 7, hr = bh & 127;
    int tid = threadIdx.x;
    int w = tid & 127;
    int og = __builtin_amdgcn_readfirstlane(tid >> 7);   // 0..3, wave-uniform
    int wl = (w + W - 1) & (W - 1), wr2 = (w + 1) & (W - 1);
    float xv[CIN][3][3];
    #pragma unroll
    for (int ic = 0; ic < CIN; ++ic) {
        const float* xc = x + (size_t)(b * CIN + ic) * HW;
        #pragma unroll
        for (int r = 0; r < 3; ++r) {
            int hh = (hr + r - 1 + H) & (H - 1);
            const float* xr = xc + hh * W;
            xv[ic][r][0] = xr[wl];
            xv[ic][r][1] = xr[w];
            xv[ic][r][2] = xr[wr2];
        }
    }
    #pragma unroll
    for (int j = 0; j < 8; ++j) {
        int o = og * 8 + j;
        float acc = pb[o];                       // uniform -> s_load
        const float* wo = pw + o * CIN * 9;      // uniform
        #pragma unroll
        for (int ic = 0; ic < CIN; ++ic)
            #pragma unroll
            for (int r = 0; r < 3; ++r)
                #pragma unroll
                for (int c3 = 0; c3 < 3; ++c3)
                    acc += xv[ic][r][c3] * wo[ic * 9 + r * 3 + c3];
        h[(size_t)(b * CH + o) * HW + hr * W + w] = f2bf(acc);
    }
}

// ---------------- DFT along W: h(bf16) rows -> Xw[row][k]{re,im} ------------
// v6: 384 thr (6 waves) -> 24 waves/CU. Wave kp=tid>>6 (0..5) owns 2 modes.
// LDS pitch 132 keeps ds_read_b128 banks rotated; staging conflict-free.
__global__ __launch_bounds__(384) void k_dft_w(
        const u16* __restrict__ h, const float* __restrict__ cnsWkw,
        float* __restrict__ Xw) {
    __shared__ float xs[64 * XPAD];      // 33.8 KB
    int row0 = blockIdx.x * 64;
    int tid = threadIdx.x;               // 0..383
    const uint2* src = (const uint2*)h;  // 4 bf16 per uint2
    #pragma unroll
    for (int it = 0; it < 6; ++it) {     // 2048 float4-slots
        int idx = it * 384 + tid;
        if (idx < 2048) {
            int r = idx >> 5, f4c = idx & 31;
            uint2 v = src[(size_t)(row0 + r) * 32 + f4c];
            float4 f;
            f.x = bflo(v.x); f.y = bfhi(v.x);
            f.z = bflo(v.y); f.w = bfhi(v.y);
            *(float4*)(xs + r * XPAD + f4c * 4) = f;
        }
    }
    __syncthreads();
    int r = tid & 63;
    int kp = __builtin_amdgcn_readfirstlane(tid >> 6);   // 0..5, wave-uniform
    const f32x2* tw = (const f32x2*)cnsWkw + kp * 2 * W; // modes 2kp, 2kp+1
    f32x2 a0 = mk2(0.f, 0.f), a1 = mk2(0.f, 0.f);
    const float4* xr4 = (const float4*)(xs + r * XPAD);
    #pragma unroll 4
    for (int w4 = 0; w4 < W / 4; ++w4) {
        float4 xv = xr4[w4];             // ds_read_b128, rotated banks
        int w = w4 * 4;
        const f32x2* t0 = tw + w;        // uniform -> batched s_loads
        const f32x2* t1 = tw + W + w;
        a0 += mk2(xv.x, xv.x) * t0[0];  a1 += mk2(xv.x, xv.x) * t1[0];
        a0 += mk2(xv.y, xv.y) * t0[1];  a1 += mk2(xv.y, xv.y) * t1[1];
        a0 += mk2(xv.z, xv.z) * t0[2];  a1 += mk2(xv.z, xv.z) * t1[2];
        a0 += mk2(xv.w, xv.w) * t0[3];  a1 += mk2(xv.w, xv.w) * t1[3];
    }
    float2* dst = (float2*)(Xw + (size_t)(row0 + r) * MODES * 2) + kp * 2;
    dst[0] = make_float2(a0.x, a0.y);
    dst[1] = make_float2(a1.x, a1.y);
}

// ---------------- DFT along H: Xw -> Xf[m][b*CH+c]{re,im} -------------------
__global__ __launch_bounds__(320) void k_dft_h(
        const float* __restrict__ Xw, const float* __restrict__ cnsH2,
        float* __restrict__ Xf) {
    __shared__ float4 xs4[H * KX / 2];   // 12 KB, aliased as float2[H][KX]
    const float2* xs = (const float2*)xs4;
    int bc = blockIdx.x;                 // 0..B*CH-1
    int tid = threadIdx.x;               // 0..319
    const float4* src = (const float4*)(Xw + (size_t)bc * H * KX * 2);
    #pragma unroll
    for (int r = 0; r < 3; ++r) {        // 768 float4 staged by 320 threads
        int idx = r * 320 + tid;
        if (idx < H * KX / 2) xs4[idx] = src[idx];
    }
    __syncthreads();
    if (tid < KY * KX) {                 // m = tid = ky*KX+kx
        int ky = tid / KX, kx = tid % KX;
        const float2* cs = (const float2*)cnsH2 + ky;   // [hh][ky] stride KY
        float ar = 0.f, ai = 0.f;
        #pragma unroll 4
        for (int hh = 0; hh < H; ++hh) {
            float2 v = xs[hh * KX + kx];                 // LDS broadcast groups
            float2 t = cs[hh * KY];                      // L1-resident table
            ar += v.x * t.x + v.y * t.y;                 // (xr+ixi)(c-is)
            ai += v.y * t.x - v.x * t.y;
        }
        ((float2*)Xf)[(size_t)tid * (B * CH) + bc] = make_float2(ar, ai);
    }
}

// ---------------- spectral channel mix: per mode, Y[b,o] = sum_i X[b,i]W[i,o]
// r18-proven: 288 blocks, 8 b's per thread (weights amortized over 8 b's;
// the r19 (288,4)x2b split quadrupled weight traffic and regressed).
__global__ __launch_bounds__(256) void k_specmul(
        const float* __restrict__ Xf, const float* __restrict__ wRl,
        float* __restrict__ Yt) {
    int m = blockIdx.x;                 // 0..287
    int o = threadIdx.x & 31;
    int bq = threadIdx.x >> 5;          // 0..7 -> 8 b's each
    const f32x2* X  = (const f32x2*)Xf  + (size_t)m * (B * CH);
    const f32x2* Wm = (const f32x2*)wRl + (size_t)m * (CH * CH);
    f32x2 acc2[8];
    #pragma unroll
    for (int j = 0; j < 8; ++j) acc2[j] = mk2(0.f, 0.f);
    for (int i = 0; i < CH; ++i) {
        f32x2 wv  = Wm[i * CH + o];     // coalesced across lanes
        f32x2 wvB = mk2(-wv.y, wv.x);
        #pragma unroll
        for (int j = 0; j < 8; ++j) {
            f32x2 xv = X[(bq * 8 + j) * CH + i];   // L1/L2 broadcast
            acc2[j] += mk2(xv.x, xv.x) * wv + mk2(xv.y, xv.y) * wvB;  // 2 pk_fma
        }
    }
    float2* Yp = (float2*)Yt;
    #pragma unroll
    for (int j = 0; j < 8; ++j)
        Yp[((size_t)(bq * 8 + j) * NMODE + m) * CH + o] = make_float2(acc2[j].x, acc2[j].y);
}

// ---------------- inverse DFT along H: Yt -> Zt[b][h][p][kx][o], pre-scaled -
// r18-proven: (B,8), 16 rows/block (y-coeff preload amortized over 16 rows;
// the r19 (B,16)x8row split doubled Yt traffic and regressed).
__global__ __launch_bounds__(384) void k_idft_h(
        const float* __restrict__ Yt, const float* __restrict__ cnsH2,
        const float* __restrict__ mnsH2, float* __restrict__ Zt) {
    int b = blockIdx.x;
    int hh0 = blockIdx.y * 16;           // 8 chunks of 16 rows
    int o = threadIdx.x & 31;
    int kx = threadIdx.x >> 5;           // 0..11
    float yr[KY], yi[KY];
    #pragma unroll
    for (int ky = 0; ky < KY; ++ky) {
        float2 v = ((const float2*)Yt)[((size_t)b * NMODE + ky * KX + kx) * CH + o];
        yr[ky] = v.x;  yi[ky] = v.y;
    }
    float sc = (kx == 0 ? 1.0f : 2.0f) / (float)HW;
    #pragma unroll 2
    for (int hr = 0; hr < 16; ++hr) {
        int hh = hh0 + hr;
        const f32x2* cs = (const f32x2*)(cnsH2 + hh * KY * 2);  // uniform
        const f32x2* ms = (const f32x2*)(mnsH2 + hh * KY * 2);  // uniform
        f32x2 a = mk2(0.f, 0.f);
        #pragma unroll
        for (int ky = 0; ky < KY; ++ky)
            a += mk2(yr[ky], yr[ky]) * cs[ky] + mk2(yi[ky], yi[ky]) * ms[ky];
        size_t base = ((size_t)(b * H + hh) * 2) * (KX * CH) + kx * CH + o;
        Zt[base]            = a.x * sc;
        Zt[base + KX * CH]  = a.y * sc;
    }
}

// ---------------- fused: pointwise GEMM + irfft(W) + bias + GELU ------------
// r15/r16 body FROZEN (84.5us equilibrium; VALU cuts no longer move it).
template <int LAST>
__global__ __launch_bounds__(512, 4) void k_fused(
        u16* __restrict__ h, const float* __restrict__ Zt,
        const float* __restrict__ wwT, const float* __restrict__ wb,
        const float* __restrict__ cWkw, const float* __restrict__ sWkw,
        float* __restrict__ part) {
    __shared__ float hs[CH * W];         // 16 KB
    __shared__ float red[8][8];          // wave partials (LAST=1 only)
    int bh = blockIdx.x;                 // b*H + hr
    int b = bh >> 7, hr = bh & 127;
    int tid = threadIdx.x;
    int w = tid & 127;
    int og = __builtin_amdgcn_readfirstlane(tid >> 7);   // wave-uniform 0..3
    const uint2* hrow2 = (const uint2*)(h + (size_t)b * CH * HW + hr * W);
    #pragma unroll
    for (int p = 0; p < 2; ++p) {        // 1024 float4-slots, conflict-free
        int idx = p * 512 + tid;
        int i = idx >> 5, f4c = idx & 31;
        uint2 v = hrow2[(size_t)i * (HW / 4) + f4c];
        float4 f;
        f.x = bflo(v.x); f.y = bfhi(v.x);
        f.z = bflo(v.y); f.w = bfhi(v.y);
        *(float4*)(hs + i * W + f4c * 4) = f;
    }
    float ck[MODES], nsk[MODES];
    #pragma unroll
    for (int k = 0; k < MODES; ++k) {
        ck[k]  = cWkw[k * W + w];        // per-lane, coalesced, L1-hot
        nsk[k] = -sWkw[k * W + w];
    }
    f32x2 acc2[4];
    const f32x2* wb2 = (const f32x2*)(wb + og * 8);      // uniform
    #pragma unroll
    for (int j = 0; j < 4; ++j) acc2[j] = wb2[j];
    __syncthreads();
    // pointwise: acc2[j] += hs[i][w] * wwT[i][og*8+2j..2j+1]
    #pragma unroll 4
    for (int i = 0; i < CH; ++i) {
        float hv = hs[i * W + w];
        f32x2 hv2 = mk2(hv, hv);
        const f32x2* wt2 = (const f32x2*)(wwT + i * CH + og * 8);  // uniform
        #pragma unroll
        for (int j = 0; j < 4; ++j) acc2[j] += hv2 * wt2[j];       // pk_fma
    }
    // spectral: acc2[j] += zr*ck - zi*sk  (pre-scaled in Zt)
    const float* Zb = Zt + ((size_t)bh * 2) * (KX * CH) + og * 8;
    #pragma unroll
    for (int k = 0; k < MODES; ++k) {
        const f32x2* zr2 = (const f32x2*)(Zb + k * CH);            // uniform
        const f32x2* zi2 = (const f32x2*)(Zb + k * CH + KX * CH);
        f32x2 ck2  = mk2(ck[k], ck[k]);
        f32x2 nsk2 = mk2(nsk[k], nsk[k]);
        #pragma unroll
        for (int j = 0; j < 4; ++j)
            acc2[j] += zr2[j] * ck2 + zi2[j] * nsk2;               // 2 pk_fma
    }
    if (LAST == 0) {
        u16* hout = h + (size_t)(b * CH + og * 8) * HW + hr * W + w;
        #pragma unroll
        for (int j = 0; j < 4; ++j) {
            u32 pk = pk2bf(gelu2(acc2[j]));          // v_cvt_pk_bf16_f32
            hout[(size_t)(2 * j)     * HW] = (u16)pk;
            hout[(size_t)(2 * j + 1) * HW] = (u16)(pk >> 16);
        }
    } else {
        float v[8];
        #pragma unroll
        for (int j = 0; j < 4; ++j) {
            f32x2 g = gelu2(acc2[j]);
            v[2 * j]     = g.x;
            v[2 * j + 1] = g.y;
        }
        #pragma unroll
        for (int j = 0; j < 8; ++j)
            #pragma unroll
            for (int off = 32; off > 0; off >>= 1)
                v[j] += __shfl_xor(v[j], off, 64);
        int wave = tid >> 6;             // 0..7 (wave>>1 == og)
        if ((tid & 63) == 0) {
            #pragma unroll
            for (int j = 0; j < 8; ++j) red[wave][j] = v[j];
        }
        __syncthreads();
        if (tid < CH) {                  // c = tid: og=c>>3, j=c&7
            float p = red[2 * (tid >> 3)][tid & 7] + red[2 * (tid >> 3) + 1][tid & 7];
            part[((size_t)b * CH + tid) * H + hr] = p;
        }
    }
}

// ---------------- head MLP (k_reduce folded in): part -> g -> 128 -> 1 ------
__global__ __launch_bounds__(128) void k_head(
        const float* __restrict__ part, const float* __restrict__ q1w,
        const float* __restrict__ q1b, const float* __restrict__ q2w,
        const float* __restrict__ q2b, float* __restrict__ out) {
    __shared__ float red3[CH][4];
    __shared__ float gs[CH];
    __shared__ float red2[2];
    int b = blockIdx.x;
    int t = threadIdx.x;
    {   // reduce part[(b,c)][0..127]: thread (c = t>>2, quarter q = t&3)
        const float* p = part + ((size_t)b * CH + (t >> 2)) * H + (t & 3) * 32;
        float s = 0.f;
        #pragma unroll
        for (int j = 0; j < 32; ++j) s += p[j];
        red3[t >> 2][t & 3] = s;
    }
    __syncthreads();
    if (t < CH)
        gs[t] = (red3[t][0] + red3[t][1] + red3[t][2] + red3[t][3]) * (1.0f / (float)HW);
    __syncthreads();
    float a = q1b[t];
    #pragma unroll
    for (int c = 0; c < CH; ++c) a += gs[c] * q1w[t * CH + c];
    a = gelu_f(a);
    float hsum = a * q2w[t];
    #pragma unroll
    for (int off = 32; off > 0; off >>= 1) hsum += __shfl_down(hsum, off, 64);
    if ((t & 63) == 0) red2[t >> 6] = hsum;
    __syncthreads();
    if (t == 0) {
        float logit = red2[0] + red2[1] + q2b[0];
        out[b] = 1.0f / (1.0f + expf(-logit));
    }
}

extern "C" void kernel_launch(void* const* d_in, const int* in_sizes, int n_in,
                              void* d_out, int out_size, void* d_ws, size_t ws_size,
                              hipStream_t stream) {
    const float* x   = (const float*)d_in[0];
    const float* p_w = (const float*)d_in[1];
    const float* p_b = (const float*)d_in[2];
    const float* w1r = (const float*)d_in[3];
    const float* w1i = (const float*)d_in[4];
    const float* w2r = (const float*)d_in[5];
    const float* w2i = (const float*)d_in[6];
    const float* ww  = (const float*)d_in[7];
    const float* wb  = (const float*)d_in[8];
    const float* q1w = (const float*)d_in[9];
    const float* q1b = (const float*)d_in[10];
    const float* q2w = (const float*)d_in[11];
    const float* q2b = (const float*)d_in[12];
    float* out = (float*)d_out;

    float* ws = (float*)d_ws;
    size_t off = 0;
    auto alloc = [&](size_t n) {
        float* p = ws + off;
        off += (n + 63) & ~(size_t)63;   // 256B-align
        return p;
    };
    float* cWkw   = alloc(MODES * W);
    float* sWkw   = alloc(MODES * W);
    float* cnsWkw = alloc(MODES * W * 2);
    float* cnsH2  = alloc(H * KY * 2);
    float* mnsH2  = alloc(H * KY * 2);
    u16*   hBuf = (u16*)alloc((size_t)B * CH * HW / 2);  // 67 MB bf16
    float* XwZ  = alloc((size_t)B * CH * H * KX * 2);    // 25 MB (Xw, reused as Zt)
    float* Xf   = alloc((size_t)NMODE * B * CH * 2);     // 4.7 MB
    float* Yt   = alloc((size_t)B * NMODE * CH * 2);     // 4.7 MB
    float* wR   = alloc((size_t)4 * NMODE * CH * CH * 2);// 9.4 MB
    float* wwT  = alloc(4 * CH * CH);
    float* part = alloc((size_t)B * CH * H);             // 1 MB block partials

    // one setup kernel: tables + ww transpose + weight reorder
    k_setup<<<(N_TBL + N_TRN + N_REO + 255) / 256, 256, 0, stream>>>(
        cWkw, sWkw, cnsWkw, cnsH2, mnsH2, w1r, w1i, w2r, w2i, wR, ww, wwT);

    k_lift<<<B * H, 512, 0, stream>>>(x, p_w, p_b, hBuf);

    for (int layer = 0; layer < 4; ++layer) {
        k_dft_w<<<(B * CH * H) / 64, 384, 0, stream>>>(hBuf, cnsWkw, XwZ);
        k_dft_h<<<B * CH, 320, 0, stream>>>(XwZ, cnsH2, Xf);
        k_specmul<<<NMODE, 256, 0, stream>>>(
            Xf, wR + (size_t)layer * NMODE * CH * CH * 2, Yt);
        k_idft_h<<<dim3(B, 8), 384, 0, stream>>>(Yt, cnsH2, mnsH2, XwZ);
        if (layer < 3)
            k_fused<0><<<B * H, 512, 0, stream>>>(
                hBuf, XwZ, wwT + layer * CH * CH, wb + layer * CH, cWkw, sWkw, part);
        else
            k_fused<1><<<B * H, 512, 0, stream>>>(
                hBuf, XwZ, wwT + layer * CH * CH, wb + layer * CH, cWkw, sWkw, part);
    }

    k_head<<<B, 128, 0, stream>>>(part, q1w, q1b, q2w, q2b, out);
}